// Round 1
// baseline (540.170 us; speedup 1.0000x reference)
//
#include <hip/hip_runtime.h>

#define N_VOX 200000
#define CI 128
#define CO 128
#define KK 27
#define BM 64
#define NBLK (N_VOX / BM)   // 3125
#define LEAK 0.333f
#define BN_EPS 1e-4f

typedef unsigned short u16;
typedef __attribute__((ext_vector_type(8))) short short8;
typedef __attribute__((ext_vector_type(4))) float f32x4;

__device__ __forceinline__ u16 f2bf(float f) {
  union { float f; unsigned u; } x; x.f = f;
  unsigned u = x.u;
  return (u16)((u + 0x7FFFu + ((u >> 16) & 1u)) >> 16);  // RNE
}

// ---- W cast + transpose: Wt[k][co][ci] = bf16(W[k][ci][co]) ----
__global__ __launch_bounds__(256) void wcast_kernel(const float* __restrict__ W,
                                                    u16* __restrict__ Wt) {
  __shared__ float tile[32][33];
  int k = blockIdx.z;
  int ci0 = blockIdx.y * 32, co0 = blockIdx.x * 32;
  const float* Wk = W + (size_t)k * CI * CO;
  u16* Wtk = Wt + (size_t)k * CI * CO;
  int tx = threadIdx.x, ty = threadIdx.y;
#pragma unroll
  for (int j = 0; j < 4; ++j)
    tile[ty + j * 8][tx] = Wk[(ci0 + ty + j * 8) * CO + co0 + tx];
  __syncthreads();
#pragma unroll
  for (int j = 0; j < 4; ++j)
    Wtk[(co0 + ty + j * 8) * CI + ci0 + tx] = f2bf(tile[tx][ty + j * 8]);
}

// ---- main conv: 64 voxels x 128 cout per block, 27-offset dense loop ----
__global__ __launch_bounds__(256) void conv_kernel(
    const float* __restrict__ feat, const u16* __restrict__ Wt,
    const int* __restrict__ nb, float* __restrict__ out,
    float* __restrict__ partial) {
  __shared__ __align__(16) u16 A_lds[BM * CI];   // 16KB, XOR-swizzled
  __shared__ __align__(16) u16 B_lds[CO * CI];   // 32KB, [co][ci], XOR-swizzled
  __shared__ int nbs[BM * KK];                   // 6.9KB

  const int tid = threadIdx.x;
  const int bid = blockIdx.x;
  const int row0 = bid * BM;

  for (int i = tid; i < BM * KK; i += 256) nbs[i] = nb[row0 * KK + i];
  __syncthreads();

  f32x4 acc[4][2];
#pragma unroll
  for (int m = 0; m < 4; ++m)
#pragma unroll
    for (int nf = 0; nf < 2; ++nf) acc[m][nf] = (f32x4){0.f, 0.f, 0.f, 0.f};

  const int lane = tid & 63;
  const int wv = tid >> 6;
  const int lr = lane & 15;
  const int lg = lane >> 4;

  const int ar = tid >> 2;         // A-stage: row 0..63
  const int ap = (tid & 3) * 32;   // A-stage: 32-elem col chunk
  const int bn_ = tid >> 1;        // B-stage: row 0..127
  const int bh = (tid & 1) * 64;   // B-stage: 64-elem col chunk

  for (int k = 0; k < KK; ++k) {
    // stage A (gather + f32->bf16), swizzled
    {
      int src = nbs[ar * KK + k];
      u16 vals[32];
      if (src >= 0) {
        const float4* fp = (const float4*)(feat + (size_t)src * CI + ap);
#pragma unroll
        for (int j = 0; j < 8; ++j) {
          float4 v = fp[j];
          vals[j * 4 + 0] = f2bf(v.x); vals[j * 4 + 1] = f2bf(v.y);
          vals[j * 4 + 2] = f2bf(v.z); vals[j * 4 + 3] = f2bf(v.w);
        }
      } else {
#pragma unroll
        for (int j = 0; j < 32; ++j) vals[j] = 0;
      }
#pragma unroll
      for (int j = 0; j < 4; ++j) {
        int idx = (ar * CI + ap + j * 8) ^ ((ar & 7) << 3);
        *(uint4*)&A_lds[idx] = *(const uint4*)&vals[j * 8];
      }
    }
    // stage B (bf16 copy of Wt[k]), swizzled
    {
      const uint4* wp = (const uint4*)(Wt + (size_t)k * CI * CO + bn_ * CI + bh);
#pragma unroll
      for (int j = 0; j < 8; ++j) {
        uint4 v = wp[j];
        int idx = (bn_ * CI + bh + j * 8) ^ ((bn_ & 7) << 3);
        *(uint4*)&B_lds[idx] = v;
      }
    }
    __syncthreads();
    // MFMA over K=128 in 4 steps of 32
#pragma unroll
    for (int ks = 0; ks < 4; ++ks) {
      const int colu = ks * 32 + lg * 8;
      short8 a[4], b[2];
#pragma unroll
      for (int m = 0; m < 4; ++m) {
        int row = m * 16 + lr;
        a[m] = *(const short8*)&A_lds[(row * CI + colu) ^ ((row & 7) << 3)];
      }
#pragma unroll
      for (int nf = 0; nf < 2; ++nf) {
        int cn = wv * 32 + nf * 16 + lr;
        b[nf] = *(const short8*)&B_lds[(cn * CI + colu) ^ ((cn & 7) << 3)];
      }
#pragma unroll
      for (int m = 0; m < 4; ++m)
#pragma unroll
        for (int nf = 0; nf < 2; ++nf)
          acc[m][nf] = __builtin_amdgcn_mfma_f32_16x16x32_bf16(a[m], b[nf], acc[m][nf], 0, 0, 0);
    }
    __syncthreads();
  }

  // epilogue: write pre-BN conv result + per-block channel sums/sumsq
#pragma unroll
  for (int nf = 0; nf < 2; ++nf) {
    int col = wv * 32 + nf * 16 + lr;
    float s = 0.f, q = 0.f;
#pragma unroll
    for (int m = 0; m < 4; ++m) {
      int rbase = row0 + m * 16 + lg * 4;
#pragma unroll
      for (int r = 0; r < 4; ++r) {
        float x = acc[m][nf][r];
        out[(size_t)(rbase + r) * CO + col] = x;
        s += x; q += x * x;
      }
    }
    s += __shfl_xor(s, 16, 64); s += __shfl_xor(s, 32, 64);
    q += __shfl_xor(q, 16, 64); q += __shfl_xor(q, 32, 64);
    if (lg == 0) {
      partial[(size_t)bid * 256 + col] = s;
      partial[(size_t)bid * 256 + 128 + col] = q;
    }
  }
}

// ---- deterministic 2-stage channel reduction ----
__global__ __launch_bounds__(256) void reduce1_kernel(const float* __restrict__ partial,
                                                      float* __restrict__ partial2) {
  int t = threadIdx.x, b = blockIdx.x;  // 125 blocks x 25 rows
  float acc = 0.f;
  for (int j = 0; j < 25; ++j) acc += partial[(size_t)(b * 25 + j) * 256 + t];
  partial2[(size_t)b * 256 + t] = acc;
}

__global__ __launch_bounds__(256) void reduce2_kernel(const float* __restrict__ partial2,
                                                      const float* __restrict__ gamma,
                                                      const float* __restrict__ beta,
                                                      float* __restrict__ stats) {
  __shared__ float sums[256];
  int t = threadIdx.x;
  float acc = 0.f;
  for (int j = 0; j < 125; ++j) acc += partial2[(size_t)j * 256 + t];
  sums[t] = acc;
  __syncthreads();
  if (t < 128) {
    float mean = sums[t] / (float)N_VOX;
    float var = sums[128 + t] / (float)N_VOX - mean * mean;
    float scale = gamma[t] * rsqrtf(var + BN_EPS);
    stats[t] = scale;
    stats[128 + t] = beta[t] - mean * scale;
  }
}

// ---- BN apply + LeakyReLU, in place on d_out ----
__global__ __launch_bounds__(256) void bnact_kernel(float* __restrict__ out,
                                                    const float* __restrict__ stats) {
  __shared__ float s_scale[128], s_shift[128];
  int t = threadIdx.x;
  if (t < 128) { s_scale[t] = stats[t]; s_shift[t] = stats[128 + t]; }
  __syncthreads();
  size_t i = (size_t)blockIdx.x * 256 + t;  // float4 index; 25000*256 == 6.4M exactly
  float4* o4 = (float4*)out;
  float4 v = o4[i];
  int c0 = ((int)(i & 31)) << 2;
  float x;
  x = v.x * s_scale[c0 + 0] + s_shift[c0 + 0]; v.x = x > 0.f ? x : LEAK * x;
  x = v.y * s_scale[c0 + 1] + s_shift[c0 + 1]; v.y = x > 0.f ? x : LEAK * x;
  x = v.z * s_scale[c0 + 2] + s_shift[c0 + 2]; v.z = x > 0.f ? x : LEAK * x;
  x = v.w * s_scale[c0 + 3] + s_shift[c0 + 3]; v.w = x > 0.f ? x : LEAK * x;
  o4[i] = v;
}

extern "C" void kernel_launch(void* const* d_in, const int* in_sizes, int n_in,
                              void* d_out, int out_size, void* d_ws, size_t ws_size,
                              hipStream_t stream) {
  const float* feat  = (const float*)d_in[0];
  const float* W     = (const float*)d_in[1];
  // d_in[2] = bias: cancels exactly under training-mode batch norm -> skipped
  const float* gamma = (const float*)d_in[3];
  const float* beta  = (const float*)d_in[4];
  const int*   nb    = (const int*)d_in[5];
  float* out = (float*)d_out;

  char* ws = (char*)d_ws;
  u16*   Wt       = (u16*)ws;                                  // 884,736 B
  float* partial  = (float*)(ws + 884736);                     // 3,200,000 B
  float* partial2 = (float*)(ws + 884736 + 3200000);           // 128,000 B
  float* stats    = (float*)(ws + 884736 + 3200000 + 128000);  // 1,024 B

  hipLaunchKernelGGL(wcast_kernel, dim3(4, 4, 27), dim3(32, 8), 0, stream, W, Wt);
  hipLaunchKernelGGL(conv_kernel, dim3(NBLK), dim3(256), 0, stream, feat, Wt, nb, out, partial);
  hipLaunchKernelGGL(reduce1_kernel, dim3(125), dim3(256), 0, stream, partial, partial2);
  hipLaunchKernelGGL(reduce2_kernel, dim3(1), dim3(256), 0, stream, partial2, gamma, beta, stats);
  hipLaunchKernelGGL(bnact_kernel, dim3(25000), dim3(256), 0, stream, out, stats);
}

// Round 2
// 302.017 us; speedup vs baseline: 1.7885x; 1.7885x over previous
//
#include <hip/hip_runtime.h>
#include <hip/hip_bf16.h>

#define N_VOX 200000
#define CI 128
#define CO 128
#define KK 27
#define BM 128
#define NBLK 1563
#define NSTEP 54
#define LEAK 0.333f
#define BN_EPS 1e-4f

typedef unsigned short u16;
typedef unsigned int u32;
typedef __attribute__((ext_vector_type(8))) short short8;
typedef __attribute__((ext_vector_type(4))) float f32x4;

typedef const __attribute__((address_space(1))) u32* gptr_t;
typedef __attribute__((address_space(3))) u32* lptr_t;

__device__ __forceinline__ u16 f2bf(float f) {  // RNE
  union { float f; u32 u; } x; x.f = f;
  return (u16)((x.u + 0x7FFFu + ((x.u >> 16) & 1u)) >> 16);
}
__device__ __forceinline__ u16 cvt_bf(float f) {
  union { __hip_bfloat16 h; u16 u; } c;
  c.h = __float2bfloat16(f);
  return c.u;
}

// ---- W cast+transpose+swizzle: Wt[k][co][ci ^ ((co&7)<<3)] = bf16(W[k][ci][co]) ----
__global__ __launch_bounds__(256) void wcast_kernel(const float* __restrict__ W,
                                                    u16* __restrict__ Wt) {
  __shared__ float tile[32][33];
  int k = blockIdx.z;
  int ci0 = blockIdx.y * 32, co0 = blockIdx.x * 32;
  const float* Wk = W + (size_t)k * CI * CO;
  u16* Wtk = Wt + (size_t)k * CI * CO;
  int tx = threadIdx.x, ty = threadIdx.y;
#pragma unroll
  for (int j = 0; j < 4; ++j)
    tile[ty + j * 8][tx] = Wk[(ci0 + ty + j * 8) * CO + co0 + tx];
  __syncthreads();
#pragma unroll
  for (int j = 0; j < 4; ++j) {
    int co = co0 + ty + j * 8;
    int ci = ci0 + tx;
    Wtk[co * CI + (ci ^ ((co & 7) << 3))] = f2bf(tile[tx][ty + j * 8]);
  }
}

// ---- main conv: 128 voxels x 128 cout per block, 54 K-half steps, dbuf pipeline ----
__global__ __launch_bounds__(256, 2) void conv_kernel(
    const float* __restrict__ feat, const u16* __restrict__ Wt,
    const int* __restrict__ nb, float* __restrict__ out,
    float* __restrict__ partial) {
  __shared__ __align__(16) char smem[79360];
  u16* const Ab0 = (u16*)smem;              // 16KB
  u16* const Ab1 = (u16*)(smem + 16384);    // 16KB
  u16* const Bb0 = (u16*)(smem + 32768);    // 16KB
  u16* const Bb1 = (u16*)(smem + 49152);    // 16KB
  int* const nbs = (int*)(smem + 65536);    // 13824B
  float* const sq = (float*)(smem + 65536); // aliases nbs (post-loop, barriered)

  const int tid = threadIdx.x;
  const int bid = blockIdx.x;
  const int row0 = bid * BM;

  for (int i = tid; i < BM * KK; i += 256) {
    int gi = row0 * KK + i;
    nbs[i] = (gi < N_VOX * KK) ? nb[gi] : -1;
  }
  __syncthreads();

  const int lane = tid & 63;
  const int wv = tid >> 6;
  const int wr = wv >> 1, wc = wv & 1;
  const int lr = lane & 15, lg = lane >> 4;
  const int arow = tid >> 1;
  const int acol = (tid & 1) * 32;  // within 64-elem K-half

  f32x4 acc[4][4];
#pragma unroll
  for (int m = 0; m < 4; ++m)
#pragma unroll
    for (int n = 0; n < 4; ++n) acc[m][n] = (f32x4){0.f, 0.f, 0.f, 0.f};

  float4 af[8];

  auto issueA = [&](int s) {  // global f32 gather -> regs
    int k = s >> 1, half = (s & 1) * 64;
    int src = nbs[arow * KK + k];
    if (src >= 0) {
      const float4* p = (const float4*)(feat + (size_t)src * CI + half + acol);
#pragma unroll
      for (int j = 0; j < 8; ++j) af[j] = p[j];
    } else {
#pragma unroll
      for (int j = 0; j < 8; ++j) af[j] = (float4){0.f, 0.f, 0.f, 0.f};
    }
  };

  auto issueB = [&](int s, u16* Bdst) {  // glds from pre-swizzled Wt
    int k = s >> 1, half = (s & 1) * 64;
    const u16* base = Wt + (size_t)k * CO * CI + half;
#pragma unroll
    for (int j = 0; j < 4; ++j) {
      int cbase = (tid >> 6) * 64 + 256 * j;  // wave-uniform chunk base
      int c = cbase + (tid & 63);
      int co = c >> 3, sub = c & 7;
      gptr_t g = (gptr_t)(base + (size_t)co * CI + sub * 8);
      __builtin_amdgcn_global_load_lds(g, (lptr_t)(Bdst + cbase * 8), 16, 0, 0);
    }
  };

  auto writeA = [&](u16* Adst) {  // cvt + swizzled ds_write
    int v = arow & 7;
#pragma unroll
    for (int q = 0; q < 4; ++q) {
      u16 t8[8];
#pragma unroll
      for (int i = 0; i < 2; ++i) {
        float4 f = af[q * 2 + i];
        t8[i * 4 + 0] = cvt_bf(f.x); t8[i * 4 + 1] = cvt_bf(f.y);
        t8[i * 4 + 2] = cvt_bf(f.z); t8[i * 4 + 3] = cvt_bf(f.w);
      }
      int c_o = (tid & 1) * 4 + q;
      *(uint4*)&Adst[arow * 64 + ((c_o ^ v) << 3)] = *(const uint4*)t8;
    }
  };

  auto compute = [&](const u16* A, const u16* B) {
#pragma unroll
    for (int ks = 0; ks < 2; ++ks) {
      short8 a[4], b[4];
#pragma unroll
      for (int m = 0; m < 4; ++m) {
        int r = wr * 64 + m * 16 + lr;
        a[m] = *(const short8*)((const char*)(A + r * 64) +
                                ((ks * 64 + lg * 16) ^ ((r & 7) << 4)));
      }
#pragma unroll
      for (int n = 0; n < 4; ++n) {
        int cn = wc * 64 + n * 16 + lr;
        b[n] = *(const short8*)((const char*)(B + cn * 64) +
                                ((ks * 64 + lg * 16) ^ ((cn & 7) << 4)));
      }
#pragma unroll
      for (int m = 0; m < 4; ++m)
#pragma unroll
        for (int n = 0; n < 4; ++n)
          acc[m][n] = __builtin_amdgcn_mfma_f32_16x16x32_bf16(a[m], b[n], acc[m][n], 0, 0, 0);
    }
  };

  issueA(0);
  issueB(0, Bb0);
  for (int s = 0; s < NSTEP - 1; ++s) {
    int pb = s & 1;
    u16* Ac = pb ? Ab1 : Ab0;
    u16* Bc = pb ? Bb1 : Bb0;
    u16* Bn = pb ? Bb0 : Bb1;
    writeA(Ac);
    __syncthreads();
    issueA(s + 1);
    issueB(s + 1, Bn);
    compute(Ac, Bc);
  }
  writeA(Ab1);
  __syncthreads();
  compute(Ab1, Bb1);

  // epilogue: out write + per-block channel sum/sumsq
  float sv[4], qv[4];
#pragma unroll
  for (int n = 0; n < 4; ++n) {
    float s = 0.f, q = 0.f;
    int col = wc * 64 + n * 16 + lr;
#pragma unroll
    for (int m = 0; m < 4; ++m) {
      int rb = row0 + wr * 64 + m * 16 + lg * 4;
#pragma unroll
      for (int e = 0; e < 4; ++e) {
        float x = acc[m][n][e];
        if (rb + e < N_VOX) out[(size_t)(rb + e) * CO + col] = x;
        s += x; q += x * x;
      }
    }
    s += __shfl_xor(s, 16, 64); s += __shfl_xor(s, 32, 64);
    q += __shfl_xor(q, 16, 64); q += __shfl_xor(q, 32, 64);
    sv[n] = s; qv[n] = q;
  }
  __syncthreads();  // nbs -> sq alias safety
  if (lg == 0) {
#pragma unroll
    for (int n = 0; n < 4; ++n) {
      int col = wc * 64 + n * 16 + lr;
      sq[wr * 256 + col] = sv[n];
      sq[wr * 256 + 128 + col] = qv[n];
    }
  }
  __syncthreads();
  partial[(size_t)bid * 256 + tid] = sq[tid] + sq[256 + tid];
}

// ---- deterministic 2-stage channel reduction ----
__global__ __launch_bounds__(256) void reduce1_kernel(const float* __restrict__ partial,
                                                      float* __restrict__ partial2) {
  int t = threadIdx.x, b = blockIdx.x;  // 98 blocks x 16 rows
  float acc = 0.f;
  int jend = (b + 1) * 16; if (jend > NBLK) jend = NBLK;
  for (int j = b * 16; j < jend; ++j) acc += partial[(size_t)j * 256 + t];
  partial2[(size_t)b * 256 + t] = acc;
}

__global__ __launch_bounds__(256) void reduce2_kernel(const float* __restrict__ partial2,
                                                      const float* __restrict__ gamma,
                                                      const float* __restrict__ beta,
                                                      float* __restrict__ stats) {
  __shared__ float sums[256];
  int t = threadIdx.x;
  float acc = 0.f;
  for (int j = 0; j < 98; ++j) acc += partial2[(size_t)j * 256 + t];
  sums[t] = acc;
  __syncthreads();
  if (t < 128) {
    float mean = sums[t] / (float)N_VOX;
    float var = sums[128 + t] / (float)N_VOX - mean * mean;
    float scale = gamma[t] * rsqrtf(var + BN_EPS);
    stats[t] = scale;
    stats[128 + t] = beta[t] - mean * scale;
  }
}

// ---- BN apply + LeakyReLU, in place on d_out ----
__global__ __launch_bounds__(256) void bnact_kernel(float* __restrict__ out,
                                                    const float* __restrict__ stats) {
  __shared__ float s_scale[128], s_shift[128];
  int t = threadIdx.x;
  if (t < 128) { s_scale[t] = stats[t]; s_shift[t] = stats[128 + t]; }
  __syncthreads();
  size_t i = (size_t)blockIdx.x * 256 + t;  // float4 index; 25000*256 == 6.4M exactly
  float4* o4 = (float4*)out;
  float4 v = o4[i];
  int c0 = ((int)(i & 31)) << 2;
  float x;
  x = v.x * s_scale[c0 + 0] + s_shift[c0 + 0]; v.x = x > 0.f ? x : LEAK * x;
  x = v.y * s_scale[c0 + 1] + s_shift[c0 + 1]; v.y = x > 0.f ? x : LEAK * x;
  x = v.z * s_scale[c0 + 2] + s_shift[c0 + 2]; v.z = x > 0.f ? x : LEAK * x;
  x = v.w * s_scale[c0 + 3] + s_shift[c0 + 3]; v.w = x > 0.f ? x : LEAK * x;
  o4[i] = v;
}

extern "C" void kernel_launch(void* const* d_in, const int* in_sizes, int n_in,
                              void* d_out, int out_size, void* d_ws, size_t ws_size,
                              hipStream_t stream) {
  const float* feat  = (const float*)d_in[0];
  const float* W     = (const float*)d_in[1];
  // d_in[2] = bias: cancels exactly under training-mode batch norm -> skipped
  const float* gamma = (const float*)d_in[3];
  const float* beta  = (const float*)d_in[4];
  const int*   nb    = (const int*)d_in[5];
  float* out = (float*)d_out;

  char* ws = (char*)d_ws;
  u16*   Wt       = (u16*)ws;                        // 884,736 B
  float* partial  = (float*)(ws + 884736);           // 1563*256*4 = 1,600,512 B
  float* partial2 = (float*)(ws + 2485248);          // 98*256*4 = 100,352 B
  float* stats    = (float*)(ws + 2585600);          // 1,024 B

  hipLaunchKernelGGL(wcast_kernel, dim3(4, 4, 27), dim3(32, 8), 0, stream, W, Wt);
  hipLaunchKernelGGL(conv_kernel, dim3(NBLK), dim3(256), 0, stream, feat, Wt, nb, out, partial);
  hipLaunchKernelGGL(reduce1_kernel, dim3(98), dim3(256), 0, stream, partial, partial2);
  hipLaunchKernelGGL(reduce2_kernel, dim3(1), dim3(256), 0, stream, partial2, gamma, beta, stats);
  hipLaunchKernelGGL(bnact_kernel, dim3(25000), dim3(256), 0, stream, out, stats);
}

// Round 3
// 288.869 us; speedup vs baseline: 1.8699x; 1.0455x over previous
//
#include <hip/hip_runtime.h>
#include <hip/hip_bf16.h>

#define N_VOX 200000
#define CI 128
#define CO 128
#define KK 27
#define BM 128
#define NBLK 1563
#define NSTEP 54
#define LEAK 0.333f
#define BN_EPS 1e-4f

typedef unsigned short u16;
typedef unsigned int u32;
typedef __attribute__((ext_vector_type(8))) short short8;
typedef __attribute__((ext_vector_type(4))) float f32x4;

typedef const __attribute__((address_space(1))) u32* gptr_t;
typedef __attribute__((address_space(3))) u32* lptr_t;

__device__ __forceinline__ u16 f2bf(float f) {  // RNE
  union { float f; u32 u; } x; x.f = f;
  return (u16)((x.u + 0x7FFFu + ((x.u >> 16) & 1u)) >> 16);
}
__device__ __forceinline__ u16 cvt_bf(float f) {
  union { __hip_bfloat16 h; u16 u; } c;
  c.h = __float2bfloat16(f);
  return c.u;
}

// ---- feature cast f32 -> bf16 (one pass, 25.6M elems, exact grid) ----
__global__ __launch_bounds__(256) void fcast_kernel(const float* __restrict__ f,
                                                    u16* __restrict__ fb) {
  size_t i = ((size_t)blockIdx.x * 256 + threadIdx.x) * 8;
  float4 a = *(const float4*)(f + i);
  float4 b = *(const float4*)(f + i + 4);
  u16 t[8];
  t[0] = cvt_bf(a.x); t[1] = cvt_bf(a.y); t[2] = cvt_bf(a.z); t[3] = cvt_bf(a.w);
  t[4] = cvt_bf(b.x); t[5] = cvt_bf(b.y); t[6] = cvt_bf(b.z); t[7] = cvt_bf(b.w);
  *(uint4*)(fb + i) = *(const uint4*)t;
}

// ---- W cast+transpose+swizzle: Wt[k][co][ci ^ ((co&7)<<3)] = bf16(W[k][ci][co]) ----
__global__ __launch_bounds__(256) void wcast_kernel(const float* __restrict__ W,
                                                    u16* __restrict__ Wt) {
  __shared__ float tile[32][33];
  int k = blockIdx.z;
  int ci0 = blockIdx.y * 32, co0 = blockIdx.x * 32;
  const float* Wk = W + (size_t)k * CI * CO;
  u16* Wtk = Wt + (size_t)k * CI * CO;
  int tx = threadIdx.x, ty = threadIdx.y;
#pragma unroll
  for (int j = 0; j < 4; ++j)
    tile[ty + j * 8][tx] = Wk[(ci0 + ty + j * 8) * CO + co0 + tx];
  __syncthreads();
#pragma unroll
  for (int j = 0; j < 4; ++j) {
    int co = co0 + ty + j * 8;
    int ci = ci0 + tx;
    Wtk[co * CI + (ci ^ ((co & 7) << 3))] = f2bf(tile[tx][ty + j * 8]);
  }
}

// ---- fast conv: A and B both staged via global_load_lds, 1 barrier/step ----
__global__ __launch_bounds__(256, 2) void conv_kernel(
    const u16* __restrict__ featb, const u16* __restrict__ Wt,
    const int* __restrict__ nb, const u16* __restrict__ zp,
    float* __restrict__ out, float* __restrict__ partial) {
  __shared__ __align__(16) char smem[79360];
  u16* const Ab0 = (u16*)smem;              // 16KB
  u16* const Ab1 = (u16*)(smem + 16384);    // 16KB
  u16* const Bb0 = (u16*)(smem + 32768);    // 16KB
  u16* const Bb1 = (u16*)(smem + 49152);    // 16KB
  int* const nbs = (int*)(smem + 65536);    // 13824B
  float* const sq = (float*)smem;           // epilogue alias (post-barrier)

  const int tid = threadIdx.x;
  const int bid = blockIdx.x;
  const int row0 = bid * BM;

  for (int i = tid; i < BM * KK; i += 256) {
    int gi = row0 * KK + i;
    nbs[i] = (gi < N_VOX * KK) ? nb[gi] : -1;
  }
  __syncthreads();

  const int lane = tid & 63;
  const int wv = tid >> 6;
  const int wr = wv >> 1, wc = wv & 1;
  const int lr = lane & 15, lg = lane >> 4;

  f32x4 acc[4][4];
#pragma unroll
  for (int m = 0; m < 4; ++m)
#pragma unroll
    for (int n = 0; n < 4; ++n) acc[m][n] = (f32x4){0.f, 0.f, 0.f, 0.f};

  // A gather: lane covers row (tid>>3)+32j, 16B chunk (lane&7); source chunk
  // pre-swizzled (m173) so linear glds dst yields the XOR layout reads expect.
  auto issueA = [&](int s, u16* Adst) {
    int k = s >> 1;
    int halfU = (s & 1) * 64;
    int r = tid >> 3;       // 0..31
    int cl = tid & 7;
#pragma unroll
    for (int j = 0; j < 4; ++j) {
      int row = j * 32 + r;
      int src = nbs[row * KK + k];
      const u16* g = (src >= 0) ? (featb + (size_t)src * CI + halfU) : zp;
      g += ((cl ^ (row & 7)) << 3);
      __builtin_amdgcn_global_load_lds((gptr_t)g, (lptr_t)(Adst + (j * 32 + wv * 8) * 64),
                                       16, 0, 0);
    }
  };

  auto issueB = [&](int s, u16* Bdst) {  // Wt pre-swizzled; linear copy
    int k = s >> 1;
    int halfU = (s & 1) * 64;
    const u16* base = Wt + (size_t)k * CI * CO + halfU;
#pragma unroll
    for (int j = 0; j < 4; ++j) {
      int cb = (j * 4 + wv) * 64;      // wave-uniform chunk base
      int c = cb + lane;
      int co = c >> 3, sub = c & 7;
      __builtin_amdgcn_global_load_lds((gptr_t)(base + co * CI + sub * 8),
                                       (lptr_t)(Bdst + cb * 8), 16, 0, 0);
    }
  };

  auto compute = [&](const u16* A, const u16* B) {
    __builtin_amdgcn_s_setprio(1);
#pragma unroll
    for (int ks = 0; ks < 2; ++ks) {
      short8 a[4], b[4];
#pragma unroll
      for (int m = 0; m < 4; ++m) {
        int r = wr * 64 + m * 16 + lr;
        a[m] = *(const short8*)((const char*)(A + r * 64) +
                                ((ks * 64 + lg * 16) ^ ((r & 7) << 4)));
      }
#pragma unroll
      for (int n = 0; n < 4; ++n) {
        int cn = wc * 64 + n * 16 + lr;
        b[n] = *(const short8*)((const char*)(B + cn * 64) +
                                ((ks * 64 + lg * 16) ^ ((cn & 7) << 4)));
      }
#pragma unroll
      for (int m = 0; m < 4; ++m)
#pragma unroll
        for (int n = 0; n < 4; ++n)
          acc[m][n] = __builtin_amdgcn_mfma_f32_16x16x32_bf16(a[m], b[n], acc[m][n], 0, 0, 0);
    }
    __builtin_amdgcn_s_setprio(0);
  };

  issueA(0, Ab0);
  issueB(0, Bb0);
  for (int s = 0; s < NSTEP; ++s) {
    __syncthreads();  // drains vmcnt(0): glds(s) landed; fences compute(s-1) vs glds(s+1)
    int pb = s & 1;
    if (s + 1 < NSTEP) {
      issueA(s + 1, pb ? Ab0 : Ab1);
      issueB(s + 1, pb ? Bb0 : Bb1);
    }
    compute(pb ? Ab1 : Ab0, pb ? Bb1 : Bb0);
  }

  // epilogue: out write + per-block channel sum/sumsq
  float sv[4], qv[4];
#pragma unroll
  for (int n = 0; n < 4; ++n) {
    float s = 0.f, q = 0.f;
    int col = wc * 64 + n * 16 + lr;
#pragma unroll
    for (int m = 0; m < 4; ++m) {
      int rb = row0 + wr * 64 + m * 16 + lg * 4;
#pragma unroll
      for (int e = 0; e < 4; ++e) {
        float x = acc[m][n][e];
        if (rb + e < N_VOX) out[(size_t)(rb + e) * CO + col] = x;
        s += x; q += x * x;
      }
    }
    s += __shfl_xor(s, 16, 64); s += __shfl_xor(s, 32, 64);
    q += __shfl_xor(q, 16, 64); q += __shfl_xor(q, 32, 64);
    sv[n] = s; qv[n] = q;
  }
  __syncthreads();
  if (lg == 0) {
#pragma unroll
    for (int n = 0; n < 4; ++n) {
      int col = wc * 64 + n * 16 + lr;
      sq[wr * 256 + col] = sv[n];
      sq[wr * 256 + 128 + col] = qv[n];
    }
  }
  __syncthreads();
  partial[(size_t)bid * 256 + tid] = sq[tid] + sq[256 + tid];
}

// ---- fallback conv (round-2 path, fp32 gather via VGPR), used if ws too small ----
__global__ __launch_bounds__(256, 2) void conv_fb_kernel(
    const float* __restrict__ feat, const u16* __restrict__ Wt,
    const int* __restrict__ nb, float* __restrict__ out,
    float* __restrict__ partial) {
  __shared__ __align__(16) char smem[79360];
  u16* const Ab0 = (u16*)smem;
  u16* const Ab1 = (u16*)(smem + 16384);
  u16* const Bb0 = (u16*)(smem + 32768);
  u16* const Bb1 = (u16*)(smem + 49152);
  int* const nbs = (int*)(smem + 65536);
  float* const sq = (float*)smem;

  const int tid = threadIdx.x;
  const int bid = blockIdx.x;
  const int row0 = bid * BM;

  for (int i = tid; i < BM * KK; i += 256) {
    int gi = row0 * KK + i;
    nbs[i] = (gi < N_VOX * KK) ? nb[gi] : -1;
  }
  __syncthreads();

  const int lane = tid & 63;
  const int wv = tid >> 6;
  const int wr = wv >> 1, wc = wv & 1;
  const int lr = lane & 15, lg = lane >> 4;
  const int arow = tid >> 1;
  const int acol = (tid & 1) * 32;

  f32x4 acc[4][4];
#pragma unroll
  for (int m = 0; m < 4; ++m)
#pragma unroll
    for (int n = 0; n < 4; ++n) acc[m][n] = (f32x4){0.f, 0.f, 0.f, 0.f};

  float4 af[8];
  auto issueA = [&](int s) {
    int k = s >> 1, half = (s & 1) * 64;
    int src = nbs[arow * KK + k];
    if (src >= 0) {
      const float4* p = (const float4*)(feat + (size_t)src * CI + half + acol);
#pragma unroll
      for (int j = 0; j < 8; ++j) af[j] = p[j];
    } else {
#pragma unroll
      for (int j = 0; j < 8; ++j) af[j] = (float4){0.f, 0.f, 0.f, 0.f};
    }
  };
  auto issueB = [&](int s, u16* Bdst) {
    int k = s >> 1, half = (s & 1) * 64;
    const u16* base = Wt + (size_t)k * CO * CI + half;
#pragma unroll
    for (int j = 0; j < 4; ++j) {
      int cb = (j * 4 + wv) * 64;
      int c = cb + lane;
      int co = c >> 3, sub = c & 7;
      __builtin_amdgcn_global_load_lds((gptr_t)(base + co * CI + sub * 8),
                                       (lptr_t)(Bdst + cb * 8), 16, 0, 0);
    }
  };
  auto writeA = [&](u16* Adst) {
    int v = arow & 7;
#pragma unroll
    for (int q = 0; q < 4; ++q) {
      u16 t8[8];
#pragma unroll
      for (int i = 0; i < 2; ++i) {
        float4 f = af[q * 2 + i];
        t8[i * 4 + 0] = cvt_bf(f.x); t8[i * 4 + 1] = cvt_bf(f.y);
        t8[i * 4 + 2] = cvt_bf(f.z); t8[i * 4 + 3] = cvt_bf(f.w);
      }
      int c_o = (tid & 1) * 4 + q;
      *(uint4*)&Adst[arow * 64 + ((c_o ^ v) << 3)] = *(const uint4*)t8;
    }
  };
  auto compute = [&](const u16* A, const u16* B) {
#pragma unroll
    for (int ks = 0; ks < 2; ++ks) {
      short8 a[4], b[4];
#pragma unroll
      for (int m = 0; m < 4; ++m) {
        int r = wr * 64 + m * 16 + lr;
        a[m] = *(const short8*)((const char*)(A + r * 64) +
                                ((ks * 64 + lg * 16) ^ ((r & 7) << 4)));
      }
#pragma unroll
      for (int n = 0; n < 4; ++n) {
        int cn = wc * 64 + n * 16 + lr;
        b[n] = *(const short8*)((const char*)(B + cn * 64) +
                                ((ks * 64 + lg * 16) ^ ((cn & 7) << 4)));
      }
#pragma unroll
      for (int m = 0; m < 4; ++m)
#pragma unroll
        for (int n = 0; n < 4; ++n)
          acc[m][n] = __builtin_amdgcn_mfma_f32_16x16x32_bf16(a[m], b[n], acc[m][n], 0, 0, 0);
    }
  };

  issueA(0);
  issueB(0, Bb0);
  for (int s = 0; s < NSTEP - 1; ++s) {
    int pb = s & 1;
    u16* Ac = pb ? Ab1 : Ab0;
    u16* Bc = pb ? Bb1 : Bb0;
    u16* Bn = pb ? Bb0 : Bb1;
    writeA(Ac);
    __syncthreads();
    issueA(s + 1);
    issueB(s + 1, Bn);
    compute(Ac, Bc);
  }
  writeA(Ab1);
  __syncthreads();
  compute(Ab1, Bb1);

  float sv[4], qv[4];
#pragma unroll
  for (int n = 0; n < 4; ++n) {
    float s = 0.f, q = 0.f;
    int col = wc * 64 + n * 16 + lr;
#pragma unroll
    for (int m = 0; m < 4; ++m) {
      int rb = row0 + wr * 64 + m * 16 + lg * 4;
#pragma unroll
      for (int e = 0; e < 4; ++e) {
        float x = acc[m][n][e];
        if (rb + e < N_VOX) out[(size_t)(rb + e) * CO + col] = x;
        s += x; q += x * x;
      }
    }
    s += __shfl_xor(s, 16, 64); s += __shfl_xor(s, 32, 64);
    q += __shfl_xor(q, 16, 64); q += __shfl_xor(q, 32, 64);
    sv[n] = s; qv[n] = q;
  }
  __syncthreads();
  if (lg == 0) {
#pragma unroll
    for (int n = 0; n < 4; ++n) {
      int col = wc * 64 + n * 16 + lr;
      sq[wr * 256 + col] = sv[n];
      sq[wr * 256 + 128 + col] = qv[n];
    }
  }
  __syncthreads();
  partial[(size_t)bid * 256 + tid] = sq[tid] + sq[256 + tid];
}

// ---- deterministic 2-stage channel reduction ----
__global__ __launch_bounds__(256) void reduce1_kernel(const float* __restrict__ partial,
                                                      float* __restrict__ partial2) {
  int t = threadIdx.x, b = blockIdx.x;
  float acc = 0.f;
  int jend = (b + 1) * 16; if (jend > NBLK) jend = NBLK;
  for (int j = b * 16; j < jend; ++j) acc += partial[(size_t)j * 256 + t];
  partial2[(size_t)b * 256 + t] = acc;
}

__global__ __launch_bounds__(256) void reduce2_kernel(const float* __restrict__ partial2,
                                                      const float* __restrict__ gamma,
                                                      const float* __restrict__ beta,
                                                      float* __restrict__ stats) {
  __shared__ float sums[256];
  int t = threadIdx.x;
  float acc = 0.f;
  for (int j = 0; j < 98; ++j) acc += partial2[(size_t)j * 256 + t];
  sums[t] = acc;
  __syncthreads();
  if (t < 128) {
    float mean = sums[t] / (float)N_VOX;
    float var = sums[128 + t] / (float)N_VOX - mean * mean;
    float scale = gamma[t] * rsqrtf(var + BN_EPS);
    stats[t] = scale;
    stats[128 + t] = beta[t] - mean * scale;
  }
}

// ---- BN apply + LeakyReLU, in place on d_out ----
__global__ __launch_bounds__(256) void bnact_kernel(float* __restrict__ out,
                                                    const float* __restrict__ stats) {
  __shared__ float s_scale[128], s_shift[128];
  int t = threadIdx.x;
  if (t < 128) { s_scale[t] = stats[t]; s_shift[t] = stats[128 + t]; }
  __syncthreads();
  size_t i = (size_t)blockIdx.x * 256 + t;
  float4* o4 = (float4*)out;
  float4 v = o4[i];
  int c0 = ((int)(i & 31)) << 2;
  float x;
  x = v.x * s_scale[c0 + 0] + s_shift[c0 + 0]; v.x = x > 0.f ? x : LEAK * x;
  x = v.y * s_scale[c0 + 1] + s_shift[c0 + 1]; v.y = x > 0.f ? x : LEAK * x;
  x = v.z * s_scale[c0 + 2] + s_shift[c0 + 2]; v.z = x > 0.f ? x : LEAK * x;
  x = v.w * s_scale[c0 + 3] + s_shift[c0 + 3]; v.w = x > 0.f ? x : LEAK * x;
  o4[i] = v;
}

extern "C" void kernel_launch(void* const* d_in, const int* in_sizes, int n_in,
                              void* d_out, int out_size, void* d_ws, size_t ws_size,
                              hipStream_t stream) {
  const float* feat  = (const float*)d_in[0];
  const float* W     = (const float*)d_in[1];
  // d_in[2] = bias: cancels exactly under training-mode batch norm -> skipped
  const float* gamma = (const float*)d_in[3];
  const float* beta  = (const float*)d_in[4];
  const int*   nb    = (const int*)d_in[5];
  float* out = (float*)d_out;

  char* ws = (char*)d_ws;
  u16*   Wt       = (u16*)ws;                        // 884,736 B
  float* partial  = (float*)(ws + 884736);           // 1,600,512 B
  float* partial2 = (float*)(ws + 2485248);          // 100,352 B
  float* stats    = (float*)(ws + 2585600);          // 1,024 B
  u16*   zp       = (u16*)(ws + 2586624);            // 256 B zeros
  u16*   featb    = (u16*)(ws + 2586880);            // 51,200,000 B
  const size_t need_fast = 2586880u + 51200000u;

  hipLaunchKernelGGL(wcast_kernel, dim3(4, 4, 27), dim3(32, 8), 0, stream, W, Wt);
  if (ws_size >= need_fast) {
    hipMemsetAsync(zp, 0, 256, stream);
    hipLaunchKernelGGL(fcast_kernel, dim3(12500), dim3(256), 0, stream, feat, featb);
    hipLaunchKernelGGL(conv_kernel, dim3(NBLK), dim3(256), 0, stream,
                       featb, Wt, nb, zp, out, partial);
  } else {
    hipLaunchKernelGGL(conv_fb_kernel, dim3(NBLK), dim3(256), 0, stream,
                       feat, Wt, nb, out, partial);
  }
  hipLaunchKernelGGL(reduce1_kernel, dim3(98), dim3(256), 0, stream, partial, partial2);
  hipLaunchKernelGGL(reduce2_kernel, dim3(1), dim3(256), 0, stream, partial2, gamma, beta, stats);
  hipLaunchKernelGGL(bnact_kernel, dim3(25000), dim3(256), 0, stream, out, stats);
}